// Round 1
// baseline (107.329 us; speedup 1.0000x reference)
//
#include <hip/hip_runtime.h>

typedef float f4 __attribute__((ext_vector_type(4)));

#define BB 32
#define CC 64
#define EE 8
#define HWX 4096   // 64*64 pixels

// ---------------------------------------------------------------------------
// Kernel 1: per-(b,c) plane reductions -> gating logits (pre-bias)
// gating_code[b,e] = sum_{c,i,j} gw[e,c,i,j] * S[b,c,i,j]
// S[i,j] = T - excludedRows(i) - excludedCols(j) + corners(i,j)
// ---------------------------------------------------------------------------
__global__ __launch_bounds__(256) void k_gate_sums(
    const float* __restrict__ x, const float* __restrict__ gate_w,
    float* __restrict__ gating) {
  __shared__ float sg[9];       // [T, r0,r1,r62,r63, c0,c1,c62,c63]
  __shared__ float cor[4][4];   // corner cells, rows/cols in {0,1,62,63}
  __shared__ float sS[9];       // the 9 window sums S[i*3+j]
  int t = threadIdx.x;
  int bc = blockIdx.x;          // b*64 + c
  int c = bc & 63;
  const float* plane = x + (size_t)bc * HWX;
  int h = t >> 2, q = t & 3;    // row h (0..63), quarter q (16 floats each)
  const f4* rp = (const f4*)(plane + h * 64 + q * 16);
  f4 a0 = rp[0], a1 = rp[1], a2 = rp[2], a3 = rp[3];
  float local = (a0[0]+a0[1]+a0[2]+a0[3]) + (a1[0]+a1[1]+a1[2]+a1[3])
              + (a2[0]+a2[1]+a2[2]+a2[3]) + (a3[0]+a3[1]+a3[2]+a3[3]);
  if (t < 9) sg[t] = 0.f;
  __syncthreads();

  bool special = (h < 2) || (h >= 62);
  int ridx = (h < 2) ? h : h - 60;   // 0,1,62,63 -> 0,1,2,3

  // wave-reduce the total, one LDS atomic per wave
  float red = local;
  #pragma unroll
  for (int off = 32; off > 0; off >>= 1) red += __shfl_down(red, off, 64);
  if ((t & 63) == 0) atomicAdd(&sg[0], red);

  if (special) atomicAdd(&sg[1 + ridx], local);          // full-row sums
  if (q == 0) {                                          // cols 0,1
    atomicAdd(&sg[5], a0[0]); atomicAdd(&sg[6], a0[1]);
    if (special) { cor[ridx][0] = a0[0]; cor[ridx][1] = a0[1]; }
  }
  if (q == 3) {                                          // cols 62,63
    atomicAdd(&sg[7], a3[2]); atomicAdd(&sg[8], a3[3]);
    if (special) { cor[ridx][2] = a3[2]; cor[ridx][3] = a3[3]; }
  }
  __syncthreads();

  if (t == 0) {
    const int EX[3][2] = {{2,3},{0,3},{0,1}};  // excluded indices per offset
    float T = sg[0];
    #pragma unroll
    for (int i = 0; i < 3; i++)
      #pragma unroll
      for (int j = 0; j < 3; j++) {
        float Re = sg[1 + EX[i][0]] + sg[1 + EX[i][1]];
        float Ce = sg[5 + EX[j][0]] + sg[5 + EX[j][1]];
        float Xc = cor[EX[i][0]][EX[j][0]] + cor[EX[i][0]][EX[j][1]]
                 + cor[EX[i][1]][EX[j][0]] + cor[EX[i][1]][EX[j][1]];
        sS[i * 3 + j] = T - Re - Ce + Xc;
      }
  }
  __syncthreads();

  if (t < EE) {
    const float* gw = gate_w + ((size_t)t * CC + c) * 9;
    float ge = 0.f;
    #pragma unroll
    for (int k = 0; k < 9; k++) ge += gw[k] * sS[k];
    int b = bc >> 6;
    atomicAdd(&gating[b * EE + t], ge);
  }
}

// ---------------------------------------------------------------------------
// Kernel 2: softmax over E=8, top-1; write expert_weights output + (scale,idx)
// ---------------------------------------------------------------------------
__global__ void k_softmax_top1(const float* __restrict__ gating,
                               const float* __restrict__ gate_b,
                               float* __restrict__ ew_out,
                               float* __restrict__ scale,
                               int* __restrict__ idxb) {
  int b = threadIdx.x;
  if (b >= BB) return;
  float g[EE];
  #pragma unroll
  for (int e = 0; e < EE; e++) g[e] = gating[b * EE + e] + 3844.0f * gate_b[e];
  int best = 0; float bg = g[0];
  #pragma unroll
  for (int e = 1; e < EE; e++) if (g[e] > bg) { bg = g[e]; best = e; }
  float s = 0.f;
  #pragma unroll
  for (int e = 0; e < EE; e++) s += expf(g[e] - bg);
  float val = 1.0f / s;   // exp(0)/sum == top-1 softmax prob
  #pragma unroll
  for (int e = 0; e < EE; e++) ew_out[b * EE + e] = (e == best) ? val : 0.f;
  scale[b] = val;
  idxb[b] = best;
}

// ---------------------------------------------------------------------------
// Kernel 3: out[b,f,p] = scale[b] * sum_c W[idx_b][f][c] * x[b,c,p]
// Block: one (b, 64-pixel tile). LDS-staged W (stride 68) and X tile.
// Thread: 4x4 (f x p) register tile, c-loop unrolled by 4 with f4 LDS reads.
// ---------------------------------------------------------------------------
__global__ __launch_bounds__(256) void k_mix(
    const float* __restrict__ x, const float* __restrict__ expert_w,
    const float* __restrict__ scale, const int* __restrict__ idxb,
    float* __restrict__ out) {
  __shared__ float Ws[64 * 68];   // stride 68 breaks bank aliasing on f-strided reads
  __shared__ float Xs[64 * 64];
  int t = threadIdx.x;
  int pt = blockIdx.x;            // pixel tile (0..63)
  int b = blockIdx.y;
  int e = idxb[b];
  float sc = scale[b];
  const float* Wg = expert_w + (size_t)e * 4096;
  const float* Xg = x + (size_t)b * 64 * 4096 + pt * 64;

  #pragma unroll
  for (int k = 0; k < 4; k++) {
    int i = t + 256 * k;
    int r = i >> 4;               // row 0..63
    int c0 = (i & 15) << 2;       // col 0..60 step 4
    f4 w = *(const f4*)(Wg + r * 64 + c0);
    *(f4*)&Ws[r * 68 + c0] = w;
    f4 xv = *(const f4*)(Xg + (size_t)r * 4096 + c0);
    *(f4*)&Xs[r * 64 + c0] = xv;
  }
  __syncthreads();

  int f0 = (t >> 4) << 2;   // 4*(t/16): output-channel tile
  int p0 = (t & 15) << 2;   // 4*(t%16): pixel tile (contiguous stores per wave)
  float acc[4][4] = {};

  for (int c0 = 0; c0 < 64; c0 += 4) {
    f4 wv[4], xv[4];
    #pragma unroll
    for (int i = 0; i < 4; i++) wv[i] = *(const f4*)&Ws[(f0 + i) * 68 + c0];
    #pragma unroll
    for (int j = 0; j < 4; j++) xv[j] = *(const f4*)&Xs[(c0 + j) * 64 + p0];
    #pragma unroll
    for (int i = 0; i < 4; i++)
      #pragma unroll
      for (int j = 0; j < 4; j++)
        #pragma unroll
        for (int p = 0; p < 4; p++)
          acc[i][p] += wv[i][j] * xv[j][p];
  }

  float* Og = out + ((size_t)(b * 64 + f0)) * 4096 + pt * 64 + p0;
  #pragma unroll
  for (int i = 0; i < 4; i++) {
    f4 r;
    r[0] = sc * acc[i][0]; r[1] = sc * acc[i][1];
    r[2] = sc * acc[i][2]; r[3] = sc * acc[i][3];
    *(f4*)(Og + (size_t)i * 4096) = r;
  }
}

// ---------------------------------------------------------------------------
extern "C" void kernel_launch(void* const* d_in, const int* in_sizes, int n_in,
                              void* d_out, int out_size, void* d_ws, size_t ws_size,
                              hipStream_t stream) {
  const float* x        = (const float*)d_in[0];   // [32,64,64,64]
  const float* gate_w   = (const float*)d_in[1];   // [8,64,3,3]
  const float* gate_b   = (const float*)d_in[2];   // [8]
  const float* expert_w = (const float*)d_in[3];   // [8,64,64]
  float* out = (float*)d_out;                      // [32,64,64,64] then [32,8]
  float* ew_out = out + (size_t)BB * CC * HWX;

  float* gating = (float*)d_ws;        // 256 floats
  float* scale  = gating + BB * EE;    // 32 floats
  int*   idxb   = (int*)(scale + BB);  // 32 ints

  hipMemsetAsync(gating, 0, BB * EE * sizeof(float), stream);
  k_gate_sums<<<BB * CC, 256, 0, stream>>>(x, gate_w, gating);
  k_softmax_top1<<<1, 64, 0, stream>>>(gating, gate_b, ew_out, scale, idxb);
  k_mix<<<dim3(64, 32), 256, 0, stream>>>(x, expert_w, scale, idxb, out);
}